// Round 4
// baseline (409.929 us; speedup 1.0000x reference)
//
#include <hip/hip_runtime.h>
#include <hip/hip_bf16.h>
#include <stdint.h>

#define SEQ 4096
#define DM 2048
#define NH 16
#define HD 128

typedef __attribute__((ext_vector_type(4)))  float f32x4;
typedef __attribute__((ext_vector_type(16))) float f32x16;
typedef __attribute__((ext_vector_type(8)))  short bf16x8;
typedef __attribute__((ext_vector_type(4)))  float float4_t;
typedef __attribute__((ext_vector_type(4)))  short s16x4;
typedef __attribute__((ext_vector_type(2)))  int   i32x2;
typedef __attribute__((ext_vector_type(2)))  unsigned u32x2;

__device__ __forceinline__ short f2bf(float f) {
  union { float f; unsigned u; } c; c.f = f;
  unsigned u = c.u;
  u += 0x7FFFu + ((u >> 16) & 1u);   // RNE
  return (short)(u >> 16);
}

__device__ __forceinline__ int cvtpk(float lo, float hi) {
  int r;
  asm("v_cvt_pk_bf16_f32 %0, %1, %2" : "=v"(r) : "v"(lo), "v"(hi));
  return r;
}

__device__ __forceinline__ void async16(const void* g, void* l) {
  __builtin_amdgcn_global_load_lds((const __attribute__((address_space(1))) void*)g,
                                   (__attribute__((address_space(3))) void*)l, 16, 0, 0);
}

__global__ __launch_bounds__(256) void rope_tables_kernel(float2* __restrict__ tab) {
  int idx = blockIdx.x * 256 + threadIdx.x;  // SEQ*64
  int s = idx >> 6, j = idx & 63;
  float invf = expf(-(float)j * (9.210340371976184f / 64.0f)); // 10000^(-j/64)
  float ang = (float)s * invf;
  tab[idx] = make_float2(cosf(ang), sinf(ang));
}

__global__ __launch_bounds__(256) void f32_to_bf16_kernel(const float* __restrict__ in,
                                                          short* __restrict__ out, int n4) {
  int stride = gridDim.x * 256;
  for (int i = blockIdx.x * 256 + threadIdx.x; i < n4; i += stride) {
    float4_t v = ((const float4_t*)in)[i];
    s16x4 r;
    #pragma unroll
    for (int u = 0; u < 4; u++) r[u] = f2bf(v[u]);
    ((s16x4*)out)[i] = r;
  }
}

// ---------------- GEMM: bf16 in, global_load_lds staging, BK=64 ------------
// C[M][N] = A[M][K] * B[N][K]^T. OUT_MODE: 0 f32, 2 bf16 transposed.
template<int OUT_MODE>
__global__ __launch_bounds__(256) void gemm_async_kernel(
    const short* __restrict__ A, const short* __restrict__ B,
    void* __restrict__ Cp, int M, int N, int K) {
  __shared__ short As[128 * 64];
  __shared__ short Bs[128 * 64];
  const int t = threadIdx.x, lane = t & 63, w = t >> 6;
  const int wr = w >> 1, wc = w & 1;
  const size_t Mbase = (size_t)blockIdx.x * 128;
  const size_t Nbase = (size_t)blockIdx.y * 128;
  f32x4 acc[4][4] = {};

  for (int k0 = 0; k0 < K; k0 += 64) {
    __syncthreads();
    #pragma unroll
    for (int c = 0; c < 4; c++) {
      int ob = w * 4096 + c * 1024;           // uniform per wave
      int o = ob + lane * 16;
      int row = o >> 7;
      int cb = (o & 127) ^ ((row & 7) << 4);
      async16((const char*)A + ((Mbase + row) * (size_t)K + k0) * 2 + cb, (char*)As + ob);
      async16((const char*)B + ((Nbase + row) * (size_t)K + k0) * 2 + cb, (char*)Bs + ob);
    }
    __syncthreads();

    bf16x8 a[2][4], b[2][4];
    #pragma unroll
    for (int ks = 0; ks < 2; ks++) {
      #pragma unroll
      for (int m = 0; m < 4; m++) {
        int row = wr * 64 + m * 16 + (lane & 15);
        int chunk = ks * 64 + (lane >> 4) * 16;
        a[ks][m] = *(const bf16x8*)((const char*)As + row * 128 + (chunk ^ ((row & 7) << 4)));
      }
      #pragma unroll
      for (int n = 0; n < 4; n++) {
        int row = wc * 64 + n * 16 + (lane & 15);
        int chunk = ks * 64 + (lane >> 4) * 16;
        b[ks][n] = *(const bf16x8*)((const char*)Bs + row * 128 + (chunk ^ ((row & 7) << 4)));
      }
    }
    #pragma unroll
    for (int ks = 0; ks < 2; ks++)
      #pragma unroll
      for (int m = 0; m < 4; m++)
        #pragma unroll
        for (int n = 0; n < 4; n++)
          acc[m][n] = __builtin_amdgcn_mfma_f32_16x16x32_bf16(a[ks][m], b[ks][n], acc[m][n], 0, 0, 0);
  }

  #pragma unroll
  for (int m = 0; m < 4; m++)
    #pragma unroll
    for (int n = 0; n < 4; n++)
      #pragma unroll
      for (int j = 0; j < 4; j++) {
        size_t row = Mbase + wr * 64 + m * 16 + (lane >> 4) * 4 + j;
        size_t col = Nbase + wc * 64 + n * 16 + (lane & 15);
        float v = acc[m][n][j];
        if (OUT_MODE == 0) ((float*)Cp)[row * N + col] = v;
        else               ((short*)Cp)[col * (size_t)M + row] = f2bf(v);
      }
}

// ---------------- GEMM + fused RoPE epilogue (Q/K projections) -------------
// Wave tiling 4x1: wave w owns rows w*32..w*32+31, all 128 cols (one head).
// IS_Q folds log2e/sqrt(HD) into Q so attention works in exp2 domain.
template<int IS_Q>
__global__ __launch_bounds__(256) void gemm_rope_kernel(
    const short* __restrict__ A, const short* __restrict__ B,
    short* __restrict__ C, const float2* __restrict__ tab) {
  __shared__ short As[128 * 64];
  __shared__ short Bs[128 * 64];
  const int t = threadIdx.x, lane = t & 63, w = t >> 6;
  const size_t Mbase = (size_t)blockIdx.x * 128;
  const size_t Nbase = (size_t)blockIdx.y * 128;
  const int K = DM;
  f32x4 acc[2][8] = {};

  for (int k0 = 0; k0 < K; k0 += 64) {
    __syncthreads();
    #pragma unroll
    for (int c = 0; c < 4; c++) {
      int ob = w * 4096 + c * 1024;
      int o = ob + lane * 16;
      int row = o >> 7;
      int cb = (o & 127) ^ ((row & 7) << 4);
      async16((const char*)A + ((Mbase + row) * (size_t)K + k0) * 2 + cb, (char*)As + ob);
      async16((const char*)B + ((Nbase + row) * (size_t)K + k0) * 2 + cb, (char*)Bs + ob);
    }
    __syncthreads();

    bf16x8 a[2][2], b[2][8];
    #pragma unroll
    for (int ks = 0; ks < 2; ks++) {
      #pragma unroll
      for (int m = 0; m < 2; m++) {
        int row = w * 32 + m * 16 + (lane & 15);
        int chunk = ks * 64 + (lane >> 4) * 16;
        a[ks][m] = *(const bf16x8*)((const char*)As + row * 128 + (chunk ^ ((row & 7) << 4)));
      }
      #pragma unroll
      for (int n = 0; n < 8; n++) {
        int row = n * 16 + (lane & 15);
        int chunk = ks * 64 + (lane >> 4) * 16;
        b[ks][n] = *(const bf16x8*)((const char*)Bs + row * 128 + (chunk ^ ((row & 7) << 4)));
      }
    }
    #pragma unroll
    for (int ks = 0; ks < 2; ks++)
      #pragma unroll
      for (int m = 0; m < 2; m++)
        #pragma unroll
        for (int n = 0; n < 8; n++)
          acc[m][n] = __builtin_amdgcn_mfma_f32_16x16x32_bf16(a[ks][m], b[ks][n], acc[m][n], 0, 0, 0);
  }

  // Q: scale = log2(e)/sqrt(128) so attention uses exp2 directly.
  const float SC = IS_Q ? 0.12751746f : 1.0f;
  #pragma unroll
  for (int m = 0; m < 2; m++)
    #pragma unroll
    for (int n = 0; n < 4; n++)
      #pragma unroll
      for (int j = 0; j < 4; j++) {
        int row = (int)Mbase + w * 32 + m * 16 + (lane >> 4) * 4 + j;   // seq pos
        int dj = n * 16 + (lane & 15);                                  // 0..63
        float2 cs = tab[row * 64 + dj];
        float cc = cs.x * SC, ss = cs.y * SC;
        float r1 = acc[m][n][j], r2 = acc[m][n + 4][j];
        C[(size_t)row * DM + Nbase + dj]      = f2bf(r1 * cc - r2 * ss);
        C[(size_t)row * DM + Nbase + dj + 64] = f2bf(r2 * cc + r1 * ss);
      }
}

// ---------------- flash attention v3b: swapped QK^T, in-register softmax ---
// 8 waves x QBLK=32 rows = 256 q-rows/block; KVBLK=64; double-buffered LDS.
// Q pre-scaled by log2e/sqrt(HD): exp2 domain. VT is [DM][SEQ].
// S^T = mfma(K,Q); O^T = mfma(VT,P^T).
// __launch_bounds__(512,2): VGPR cap 256 -- live set ~180, r3's default cap
// (~112) spilled ~15MB/launch to scratch (WRITE_SIZE 31.7MB vs 16.4MB ideal).
__global__ __launch_bounds__(512, 2) void flash_attn3_kernel(
    const short* __restrict__ Q, const short* __restrict__ K,
    const short* __restrict__ VT, short* __restrict__ O) {
  __shared__ short Ks[2][64 * 128];   // [key][d], rows 256B, slot^=(row&15)
  __shared__ short Vs[2][128 * 64];   // [d][key], rows 128B, slot^=(row&7)
  const int t = threadIdx.x, lane = t & 63, w = t >> 6;
  const int hi = lane >> 5, c31 = lane & 31;
  const int id = blockIdx.x;                    // 0..255
  const int h  = (id & 7) * 2 + ((id >> 3) & 1);  // 2 heads per XCD
  const int pr = id >> 4;                       // 0..15

  auto stage = [&](int kt, int buf) {
    #pragma unroll
    for (int it = 0; it < 2; it++) {
      const int ob = it * 8192 + w * 1024;      // wave-uniform LDS byte base
      const int o  = ob + lane * 16;
      { const int row = o >> 8, x = o & 255;
        const size_t src = ((size_t)(kt * 64 + row) * DM + h * HD) * 2
                         + (size_t)(x ^ ((row & 15) << 4));
        async16((const char*)K + src, (char*)&Ks[buf][0] + ob); }
      { const int row = o >> 7, x = o & 127;
        const size_t src = ((size_t)(h * HD + row) * SEQ + (size_t)kt * 64) * 2
                         + (size_t)(x ^ ((row & 7) << 4));
        async16((const char*)VT + src, (char*)&Vs[buf][0] + ob); }
    }
  };

  for (int rep = 0; rep < 2; rep++) {
    const int qt = rep ? (15 - pr) : pr;
    const int q0 = qt * 256;
    const int nt = (qt + 1) * 4;
    const int qrow = q0 + w * 32 + c31;         // this lane's q-row

    // Q fragments (B-operand): lane holds Q[qrow][16s+8hi .. +7]
    bf16x8 qf[8];
    #pragma unroll
    for (int s = 0; s < 8; s++)
      qf[s] = *(const bf16x8*)(Q + (size_t)qrow * DM + h * HD + s * 16 + hi * 8);

    f32x16 oacc[4] = {};
    float m = -3.0e38f, l = 0.f;

    stage(0, 0);
    __syncthreads();

    for (int kt = 0; kt < nt; kt++) {
      const int buf = kt & 1;
      if (kt + 1 < nt) stage(kt + 1, buf ^ 1);

      if (64 * kt <= q0 + 32 * w + 31) {        // wave has unmasked work
        // ---- S^T = K Q^T : lane gets q-col=c31, keys crow(r,hi)+32a ----
        f32x16 sacc[2] = {};
        __builtin_amdgcn_s_setprio(1);
        #pragma unroll
        for (int a = 0; a < 2; a++)
          #pragma unroll
          for (int s = 0; s < 8; s++) {
            int row = a * 32 + c31;
            bf16x8 kf = *(const bf16x8*)((const char*)&Ks[buf][0] + row * 256
                                         + ((s * 32 + hi * 16) ^ ((row & 15) << 4)));
            sacc[a] = __builtin_amdgcn_mfma_f32_32x32x16_bf16(kf, qf[s], sacc[a], 0, 0, 0);
          }
        __builtin_amdgcn_s_setprio(0);

        // ---- in-lane max over 32 raw scores (log2-domain), pair-combine ----
        float t0[16];
        #pragma unroll
        for (int r = 0; r < 16; r++) t0[r] = fmaxf(sacc[0][r], sacc[1][r]);
        #pragma unroll
        for (int d = 8; d > 0; d >>= 1)
          #pragma unroll
          for (int r = 0; r < 8; r++) if (r < d) t0[r] = fmaxf(t0[r], t0[r + d]);
        float mx = t0[0];
        i32x2 mm = __builtin_amdgcn_permlane32_swap(__float_as_int(mx), __float_as_int(mx),
                                                    false, false);
        mx = fmaxf(__int_as_float(mm.x), __int_as_float(mm.y));

        // ---- defer-max rescale (THR = 8/ln2 in log2 domain) ----
        if (__any(mx > m + 11.5416f)) {
          float mn = fmaxf(m, mx);
          float al = exp2f(m - mn);
          m = mn; l *= al;
          #pragma unroll
          for (int g = 0; g < 4; g++)
            #pragma unroll
            for (int r = 0; r < 16; r++) oacc[g][r] *= al;
        }

        // ---- exp2 + causal mask (mask only forces e=0) ----
        const bool maskT = (64 * kt + 63) > (q0 + 32 * w);
        #pragma unroll
        for (int a = 0; a < 2; a++)
          #pragma unroll
          for (int r = 0; r < 16; r++) {
            float e = exp2f(sacc[a][r] - m);
            if (maskT) {
              int key = 64 * kt + a * 32 + ((r >> 2) * 8) + (r & 3) + 4 * hi;
              e = (key > qrow) ? 0.f : e;
            }
            sacc[a][r] = e;
          }

        // ---- in-lane sum (l stays per-lane-half; combined at the end) ----
        float s0[16];
        #pragma unroll
        for (int r = 0; r < 16; r++) s0[r] = sacc[0][r] + sacc[1][r];
        #pragma unroll
        for (int d = 8; d > 0; d >>= 1)
          #pragma unroll
          for (int r = 0; r < 8; r++) if (r < d) s0[r] = s0[r] + s0[r + d];
        l += s0[0];

        // ---- P^T B-fragments via cvt_pk + permlane32_swap (T12) ----
        bf16x8 pa[4];
        #pragma unroll
        for (int a = 0; a < 2; a++)
          #pragma unroll
          for (int s = 0; s < 2; s++) {
            int q0a = cvtpk(sacc[a][8 * s + 0], sacc[a][8 * s + 1]);   // q0(2s)
            int q1a = cvtpk(sacc[a][8 * s + 2], sacc[a][8 * s + 3]);   // q1(2s)
            int q0b = cvtpk(sacc[a][8 * s + 4], sacc[a][8 * s + 5]);   // q0(2s+1)
            int q1b = cvtpk(sacc[a][8 * s + 6], sacc[a][8 * s + 7]);   // q1(2s+1)
            i32x2 r0 = __builtin_amdgcn_permlane32_swap(q0a, q0b, false, false);
            i32x2 r1 = __builtin_amdgcn_permlane32_swap(q1a, q1b, false, false);
            union { int d[4]; bf16x8 v; } u;
            u.d[0] = r0.x; u.d[1] = r1.x; u.d[2] = r0.y; u.d[3] = r1.y;
            pa[a * 2 + s] = u.v;
          }

        // ---- O^T += V^T P^T ----
        __builtin_amdgcn_s_setprio(1);
        #pragma unroll
        for (int sg = 0; sg < 4; sg++)
          #pragma unroll
          for (int g = 0; g < 4; g++) {
            int row = g * 32 + c31;
            bf16x8 vf = *(const bf16x8*)((const char*)&Vs[buf][0] + row * 128
                                         + ((sg * 32 + hi * 16) ^ ((row & 7) << 4)));
            oacc[g] = __builtin_amdgcn_mfma_f32_32x32x16_bf16(vf, pa[sg], oacc[g], 0, 0, 0);
          }
        __builtin_amdgcn_s_setprio(0);
      }
      __syncthreads();   // drains staged loads; all waves done with buf
    }

    // ---- combine l across the lane pair, normalize, write O ----
    i32x2 lr = __builtin_amdgcn_permlane32_swap(__float_as_int(l), __float_as_int(l),
                                                false, false);
    float ltot = __int_as_float(lr.x) + __int_as_float(lr.y);
    float inv = 1.0f / ltot;
    #pragma unroll
    for (int g = 0; g < 4; g++)
      #pragma unroll
      for (int tt = 0; tt < 4; tt++) {
        u32x2 pk;
        pk.x = (unsigned)cvtpk(oacc[g][4 * tt + 0] * inv, oacc[g][4 * tt + 1] * inv);
        pk.y = (unsigned)cvtpk(oacc[g][4 * tt + 2] * inv, oacc[g][4 * tt + 3] * inv);
        *(u32x2*)(O + (size_t)qrow * DM + h * HD + g * 32 + tt * 8 + hi * 4) = pk;
      }
  }
}

extern "C" void kernel_launch(void* const* d_in, const int* in_sizes, int n_in,
                              void* d_out, int out_size, void* d_ws, size_t ws_size,
                              hipStream_t stream) {
  const float* x  = (const float*)d_in[0];
  const float* wq = (const float*)d_in[1];
  const float* wk = (const float*)d_in[2];
  const float* wv = (const float*)d_in[3];
  const float* wo = (const float*)d_in[4];
  float* out = (float*)d_out;

  const size_t SQDMs = (size_t)SEQ * DM;   // 8M elements
  short* Qb   = (short*)d_ws;
  short* Kb   = Qb + SQDMs;
  short* VTb  = Kb + SQDMs;
  short* Cb   = VTb + SQDMs;
  short* xbf  = Cb + SQDMs;
  short* wbuf = xbf + SQDMs;
  float2* tab = (float2*)(wbuf + (size_t)DM * DM);

  rope_tables_kernel<<<SEQ * 64 / 256, 256, 0, stream>>>(tab);
  f32_to_bf16_kernel<<<2048, 256, 0, stream>>>(x, xbf, (int)(SQDMs / 4));

  dim3 g(SEQ / 128, DM / 128);
  f32_to_bf16_kernel<<<2048, 256, 0, stream>>>(wq, wbuf, DM * DM / 4);
  gemm_rope_kernel<1><<<g, 256, 0, stream>>>(xbf, wbuf, Qb, tab);
  f32_to_bf16_kernel<<<2048, 256, 0, stream>>>(wk, wbuf, DM * DM / 4);
  gemm_rope_kernel<0><<<g, 256, 0, stream>>>(xbf, wbuf, Kb, tab);
  f32_to_bf16_kernel<<<2048, 256, 0, stream>>>(wv, wbuf, DM * DM / 4);
  gemm_async_kernel<2><<<g, 256, 0, stream>>>(xbf, wbuf, VTb, SEQ, DM, DM);

  flash_attn3_kernel<<<256, 512, 0, stream>>>(Qb, Kb, VTb, Cb);

  f32_to_bf16_kernel<<<2048, 256, 0, stream>>>(wo, wbuf, DM * DM / 4);
  gemm_async_kernel<0><<<g, 256, 0, stream>>>(Cb, wbuf, out, SEQ, DM, DM);
}

// Round 5
// 315.501 us; speedup vs baseline: 1.2993x; 1.2993x over previous
//
#include <hip/hip_runtime.h>
#include <hip/hip_bf16.h>
#include <stdint.h>

#define SEQ 4096
#define DM 2048
#define NH 16
#define HD 128

typedef __attribute__((ext_vector_type(4)))  float f32x4;
typedef __attribute__((ext_vector_type(16))) float f32x16;
typedef __attribute__((ext_vector_type(8)))  short bf16x8;
typedef __attribute__((ext_vector_type(4)))  float float4_t;
typedef __attribute__((ext_vector_type(4)))  short s16x4;
typedef __attribute__((ext_vector_type(2)))  int   i32x2;
typedef __attribute__((ext_vector_type(2)))  unsigned u32x2;

__device__ __forceinline__ short f2bf(float f) {
  union { float f; unsigned u; } c; c.f = f;
  unsigned u = c.u;
  u += 0x7FFFu + ((u >> 16) & 1u);   // RNE
  return (short)(u >> 16);
}

__device__ __forceinline__ int cvtpk(float lo, float hi) {
  int r;
  asm("v_cvt_pk_bf16_f32 %0, %1, %2" : "=v"(r) : "v"(lo), "v"(hi));
  return r;
}

__device__ __forceinline__ void async16(const void* g, void* l) {
  __builtin_amdgcn_global_load_lds((const __attribute__((address_space(1))) void*)g,
                                   (__attribute__((address_space(3))) void*)l, 16, 0, 0);
}

__global__ __launch_bounds__(256) void rope_tables_kernel(float2* __restrict__ tab) {
  int idx = blockIdx.x * 256 + threadIdx.x;  // SEQ*64
  int s = idx >> 6, j = idx & 63;
  float invf = expf(-(float)j * (9.210340371976184f / 64.0f)); // 10000^(-j/64)
  float ang = (float)s * invf;
  tab[idx] = make_float2(cosf(ang), sinf(ang));
}

__global__ __launch_bounds__(256) void f32_to_bf16_kernel(const float* __restrict__ in,
                                                          short* __restrict__ out, int n4) {
  int stride = gridDim.x * 256;
  for (int i = blockIdx.x * 256 + threadIdx.x; i < n4; i += stride) {
    float4_t v = ((const float4_t*)in)[i];
    s16x4 r;
    #pragma unroll
    for (int u = 0; u < 4; u++) r[u] = f2bf(v[u]);
    ((s16x4*)out)[i] = r;
  }
}

// ---------------- GEMM: bf16 in, global_load_lds staging, BK=64 ------------
// C[M][N] = A[M][K] * B[N][K]^T. OUT_MODE: 0 f32, 2 bf16 transposed.
template<int OUT_MODE>
__global__ __launch_bounds__(256) void gemm_async_kernel(
    const short* __restrict__ A, const short* __restrict__ B,
    void* __restrict__ Cp, int M, int N, int K) {
  __shared__ short As[128 * 64];
  __shared__ short Bs[128 * 64];
  const int t = threadIdx.x, lane = t & 63, w = t >> 6;
  const int wr = w >> 1, wc = w & 1;
  const size_t Mbase = (size_t)blockIdx.x * 128;
  const size_t Nbase = (size_t)blockIdx.y * 128;
  f32x4 acc[4][4] = {};

  for (int k0 = 0; k0 < K; k0 += 64) {
    __syncthreads();
    #pragma unroll
    for (int c = 0; c < 4; c++) {
      int ob = w * 4096 + c * 1024;           // uniform per wave
      int o = ob + lane * 16;
      int row = o >> 7;
      int cb = (o & 127) ^ ((row & 7) << 4);
      async16((const char*)A + ((Mbase + row) * (size_t)K + k0) * 2 + cb, (char*)As + ob);
      async16((const char*)B + ((Nbase + row) * (size_t)K + k0) * 2 + cb, (char*)Bs + ob);
    }
    __syncthreads();

    bf16x8 a[2][4], b[2][4];
    #pragma unroll
    for (int ks = 0; ks < 2; ks++) {
      #pragma unroll
      for (int m = 0; m < 4; m++) {
        int row = wr * 64 + m * 16 + (lane & 15);
        int chunk = ks * 64 + (lane >> 4) * 16;
        a[ks][m] = *(const bf16x8*)((const char*)As + row * 128 + (chunk ^ ((row & 7) << 4)));
      }
      #pragma unroll
      for (int n = 0; n < 4; n++) {
        int row = wc * 64 + n * 16 + (lane & 15);
        int chunk = ks * 64 + (lane >> 4) * 16;
        b[ks][n] = *(const bf16x8*)((const char*)Bs + row * 128 + (chunk ^ ((row & 7) << 4)));
      }
    }
    #pragma unroll
    for (int ks = 0; ks < 2; ks++)
      #pragma unroll
      for (int m = 0; m < 4; m++)
        #pragma unroll
        for (int n = 0; n < 4; n++)
          acc[m][n] = __builtin_amdgcn_mfma_f32_16x16x32_bf16(a[ks][m], b[ks][n], acc[m][n], 0, 0, 0);
  }

  #pragma unroll
  for (int m = 0; m < 4; m++)
    #pragma unroll
    for (int n = 0; n < 4; n++)
      #pragma unroll
      for (int j = 0; j < 4; j++) {
        size_t row = Mbase + wr * 64 + m * 16 + (lane >> 4) * 4 + j;
        size_t col = Nbase + wc * 64 + n * 16 + (lane & 15);
        float v = acc[m][n][j];
        if (OUT_MODE == 0) ((float*)Cp)[row * N + col] = v;
        else               ((short*)Cp)[col * (size_t)M + row] = f2bf(v);
      }
}

// ---------------- GEMM + fused RoPE epilogue (Q/K projections) -------------
// Wave tiling 4x1: wave w owns rows w*32..w*32+31, all 128 cols (one head).
// IS_Q folds log2e/sqrt(HD) into Q so attention works in exp2 domain.
template<int IS_Q>
__global__ __launch_bounds__(256) void gemm_rope_kernel(
    const short* __restrict__ A, const short* __restrict__ B,
    short* __restrict__ C, const float2* __restrict__ tab) {
  __shared__ short As[128 * 64];
  __shared__ short Bs[128 * 64];
  const int t = threadIdx.x, lane = t & 63, w = t >> 6;
  const size_t Mbase = (size_t)blockIdx.x * 128;
  const size_t Nbase = (size_t)blockIdx.y * 128;
  const int K = DM;
  f32x4 acc[2][8] = {};

  for (int k0 = 0; k0 < K; k0 += 64) {
    __syncthreads();
    #pragma unroll
    for (int c = 0; c < 4; c++) {
      int ob = w * 4096 + c * 1024;
      int o = ob + lane * 16;
      int row = o >> 7;
      int cb = (o & 127) ^ ((row & 7) << 4);
      async16((const char*)A + ((Mbase + row) * (size_t)K + k0) * 2 + cb, (char*)As + ob);
      async16((const char*)B + ((Nbase + row) * (size_t)K + k0) * 2 + cb, (char*)Bs + ob);
    }
    __syncthreads();

    bf16x8 a[2][2], b[2][8];
    #pragma unroll
    for (int ks = 0; ks < 2; ks++) {
      #pragma unroll
      for (int m = 0; m < 2; m++) {
        int row = w * 32 + m * 16 + (lane & 15);
        int chunk = ks * 64 + (lane >> 4) * 16;
        a[ks][m] = *(const bf16x8*)((const char*)As + row * 128 + (chunk ^ ((row & 7) << 4)));
      }
      #pragma unroll
      for (int n = 0; n < 8; n++) {
        int row = n * 16 + (lane & 15);
        int chunk = ks * 64 + (lane >> 4) * 16;
        b[ks][n] = *(const bf16x8*)((const char*)Bs + row * 128 + (chunk ^ ((row & 7) << 4)));
      }
    }
    #pragma unroll
    for (int ks = 0; ks < 2; ks++)
      #pragma unroll
      for (int m = 0; m < 2; m++)
        #pragma unroll
        for (int n = 0; n < 8; n++)
          acc[m][n] = __builtin_amdgcn_mfma_f32_16x16x32_bf16(a[ks][m], b[ks][n], acc[m][n], 0, 0, 0);
  }

  // Q: scale = log2(e)/sqrt(128) so attention uses exp2 directly.
  const float SC = IS_Q ? 0.12751746f : 1.0f;
  #pragma unroll
  for (int m = 0; m < 2; m++)
    #pragma unroll
    for (int n = 0; n < 4; n++)
      #pragma unroll
      for (int j = 0; j < 4; j++) {
        int row = (int)Mbase + w * 32 + m * 16 + (lane >> 4) * 4 + j;   // seq pos
        int dj = n * 16 + (lane & 15);                                  // 0..63
        float2 cs = tab[row * 64 + dj];
        float cc = cs.x * SC, ss = cs.y * SC;
        float r1 = acc[m][n][j], r2 = acc[m][n + 4][j];
        C[(size_t)row * DM + Nbase + dj]      = f2bf(r1 * cc - r2 * ss);
        C[(size_t)row * DM + Nbase + dj + 64] = f2bf(r2 * cc + r1 * ss);
      }
}

// ---------------- flash attention v4: QBLK=128, KVBLK=128, kv-split --------
// 8 waves = 4 q-strips (32 rows) x 2 kv-halves (64 keys). Each wave keeps
// partial (m,l,oacc) over its key-half; halves merge through LDS at rep end.
// Pairs (p, 31-p): every block = 33 kv-steps (balanced). Grid 256 = 1/CU.
// Q pre-scaled by log2e/sqrt(HD) (exp2 domain). VT is [DM][SEQ].
// S^T = mfma(K,Q); O^T = mfma(VT,P^T).
__global__ __launch_bounds__(512) void flash_attn4_kernel(
    const short* __restrict__ Q, const short* __restrict__ K,
    const short* __restrict__ VT, short* __restrict__ O) {
  // LDS map: [0,32K)=Ks0 [32K,64K)=Ks1 [64K,96K)=Vs0 [96K,128K)=Vs1
  // merge overlay: Opart fp32 [4 strip][128 d][32 q] on [0,64K); ml at 128K.
  __shared__ __align__(16) char LB[132096];
  const int t = threadIdx.x, lane = t & 63, w = t >> 6;
  const int hi = lane >> 5, c31 = lane & 31;
  const int s = w & 3, v = w >> 2;
  const int id = blockIdx.x;                      // 0..255
  const int h  = (id & 7) * 2 + ((id >> 3) & 1);  // 2 heads per XCD
  const int pr = id >> 4;                         // 0..15

  float* Opart = (float*)LB;                  // [s][d][q]
  float* ml    = (float*)(LB + 131072);       // [s][q][2]

  auto stage = [&](int kt, int buf) {
    #pragma unroll
    for (int it = 0; it < 4; it++) {
      const int ob = w * 4096 + it * 1024;    // wave-uniform LDS byte base
      const int o  = ob + lane * 16;
      const int row = o >> 8;
      const int xs = (o & 255) ^ ((row & 15) << 4);
      async16((const char*)K + ((size_t)(kt * 128 + row) * DM + h * HD) * 2 + xs,
              LB + buf * 32768 + ob);
      async16((const char*)VT + ((size_t)(h * HD + row) * SEQ + (size_t)kt * 128) * 2 + xs,
              LB + 65536 + buf * 32768 + ob);
    }
  };

  for (int rep = 0; rep < 2; rep++) {
    const int qt = rep ? (31 - pr) : pr;        // tiles of 128 rows; single cover
    const int q0 = qt * 128;
    const int nt = qt + 1;
    const int qrow = q0 + s * 32 + c31;         // this lane's q-row

    __syncthreads();                            // prior rep's merge reads done
    stage(0, 0);

    // Q fragments (B-operand): lane holds Q[qrow][16ss+8hi .. +7]
    bf16x8 qf[8];
    #pragma unroll
    for (int ss = 0; ss < 8; ss++)
      qf[ss] = *(const bf16x8*)(Q + (size_t)qrow * DM + h * HD + ss * 16 + hi * 8);

    f32x16 oacc[4] = {};
    float m = -3.0e38f, l = 0.f;

    __syncthreads();                            // stage(0) landed (vmcnt drain)

    for (int kt = 0; kt < nt; kt++) {
      const int buf = kt & 1;
      if (kt + 1 < nt) stage(kt + 1, buf ^ 1);

      if (kt * 128 + v * 64 <= q0 + s * 32 + 31) {   // wave has unmasked work
        const char* KsB = LB + buf * 32768;
        const char* VsB = LB + 65536 + buf * 32768;

        // ---- S^T = K Q^T : keys [64v,64v+64), q-col = c31 ----
        f32x16 sacc[2] = {};
        __builtin_amdgcn_s_setprio(1);
        #pragma unroll
        for (int a = 0; a < 2; a++)
          #pragma unroll
          for (int ss = 0; ss < 8; ss++) {
            int row = v * 64 + a * 32 + c31;
            bf16x8 kf = *(const bf16x8*)(KsB + row * 256
                                         + ((ss * 32 + hi * 16) ^ ((row & 15) << 4)));
            sacc[a] = __builtin_amdgcn_mfma_f32_32x32x16_bf16(kf, qf[ss], sacc[a], 0, 0, 0);
          }
        __builtin_amdgcn_s_setprio(0);

        // ---- per-q max over the wave's 64 keys (log2 domain) ----
        float t0[16];
        #pragma unroll
        for (int r = 0; r < 16; r++) t0[r] = fmaxf(sacc[0][r], sacc[1][r]);
        #pragma unroll
        for (int d = 8; d > 0; d >>= 1)
          #pragma unroll
          for (int r = 0; r < 8; r++) if (r < d) t0[r] = fmaxf(t0[r], t0[r + d]);
        float mx = t0[0];
        i32x2 mm = __builtin_amdgcn_permlane32_swap(__float_as_int(mx), __float_as_int(mx),
                                                    false, false);
        mx = fmaxf(__int_as_float(mm.x), __int_as_float(mm.y));

        // ---- defer-max rescale (THR = 8/ln2 in log2 domain) ----
        if (__any(mx > m + 11.5416f)) {
          float mn = fmaxf(m, mx);
          float al = exp2f(m - mn);
          m = mn; l *= al;
          #pragma unroll
          for (int g = 0; g < 4; g++)
            #pragma unroll
            for (int r = 0; r < 16; r++) oacc[g][r] *= al;
        }

        // ---- exp2 + causal mask ----
        const int rel = qrow - kt * 128 - v * 64;     // keep key_local <= rel
        const bool maskT = (kt * 128 + v * 64 + 63) > (q0 + s * 32);
        #pragma unroll
        for (int a = 0; a < 2; a++)
          #pragma unroll
          for (int r = 0; r < 16; r++) {
            float e = exp2f(sacc[a][r] - m);
            if (maskT) {
              int kl = a * 32 + (r & 3) + 8 * (r >> 2) + 4 * hi;
              e = (kl > rel) ? 0.f : e;
            }
            sacc[a][r] = e;
          }

        // ---- per-(hi,q) sum -> l ----
        float s0[16];
        #pragma unroll
        for (int r = 0; r < 16; r++) s0[r] = sacc[0][r] + sacc[1][r];
        #pragma unroll
        for (int d = 8; d > 0; d >>= 1)
          #pragma unroll
          for (int r = 0; r < 8; r++) if (r < d) s0[r] = s0[r] + s0[r + d];
        l += s0[0];

        // ---- P^T B-fragments via cvt_pk + permlane32_swap (T12) ----
        bf16x8 pa[4];
        #pragma unroll
        for (int a = 0; a < 2; a++)
          #pragma unroll
          for (int sg = 0; sg < 2; sg++) {
            int q0a = cvtpk(sacc[a][8 * sg + 0], sacc[a][8 * sg + 1]);
            int q1a = cvtpk(sacc[a][8 * sg + 2], sacc[a][8 * sg + 3]);
            int q0b = cvtpk(sacc[a][8 * sg + 4], sacc[a][8 * sg + 5]);
            int q1b = cvtpk(sacc[a][8 * sg + 6], sacc[a][8 * sg + 7]);
            i32x2 r0 = __builtin_amdgcn_permlane32_swap(q0a, q0b, false, false);
            i32x2 r1 = __builtin_amdgcn_permlane32_swap(q1a, q1b, false, false);
            union { int d[4]; bf16x8 vv; } u;
            u.d[0] = r0.x; u.d[1] = r1.x; u.d[2] = r0.y; u.d[3] = r1.y;
            pa[a * 2 + sg] = u.vv;
          }

        // ---- partial O^T += V^T P^T over keys [64v, 64v+64) ----
        __builtin_amdgcn_s_setprio(1);
        #pragma unroll
        for (int ks = 0; ks < 4; ks++)
          #pragma unroll
          for (int g = 0; g < 4; g++) {
            int row = g * 32 + c31;
            bf16x8 vf = *(const bf16x8*)(VsB + row * 256
                         + (((v * 64 + ks * 16 + hi * 8) * 2) ^ ((row & 15) << 4)));
            oacc[g] = __builtin_amdgcn_mfma_f32_32x32x16_bf16(vf, pa[ks], oacc[g], 0, 0, 0);
          }
        __builtin_amdgcn_s_setprio(0);
      }
      __syncthreads();   // staged loads landed; all waves done with buf
    }

    // ---- combine l across the hi pair (m already shared) ----
    i32x2 lr = __builtin_amdgcn_permlane32_swap(__float_as_int(l), __float_as_int(l),
                                                false, false);
    l = __int_as_float(lr.x) + __int_as_float(lr.y);

    // ---- merge kv-halves: v==1 publishes, v==0 combines & writes ----
    if (v == 1) {
      #pragma unroll
      for (int g = 0; g < 4; g++)
        #pragma unroll
        for (int r = 0; r < 16; r++) {
          int d = g * 32 + (r & 3) + 8 * (r >> 2) + 4 * hi;
          Opart[s * 4096 + d * 32 + c31] = oacc[g][r];
        }
      if (hi == 0) {
        ml[(s * 32 + c31) * 2]     = m;
        ml[(s * 32 + c31) * 2 + 1] = l;
      }
    }
    __syncthreads();
    if (v == 0) {
      float lB = ml[(s * 32 + c31) * 2 + 1];
      float mB = (lB > 0.f) ? ml[(s * 32 + c31) * 2] : -3.0e38f;
      float ms = fmaxf(m, mB);
      float aA = exp2f(m - ms), aB = exp2f(mB - ms);
      float linv = 1.0f / (l * aA + lB * aB);
      float sA = aA * linv, sB = aB * linv;
      #pragma unroll
      for (int g = 0; g < 4; g++)
        #pragma unroll
        for (int tt = 0; tt < 4; tt++) {
          float o[4];
          #pragma unroll
          for (int e = 0; e < 4; e++) {
            int d = g * 32 + e + 8 * tt + 4 * hi;
            o[e] = oacc[g][4 * tt + e] * sA + Opart[s * 4096 + d * 32 + c31] * sB;
          }
          u32x2 pk;
          pk.x = (unsigned)cvtpk(o[0], o[1]);
          pk.y = (unsigned)cvtpk(o[2], o[3]);
          *(u32x2*)(O + (size_t)qrow * DM + h * HD + g * 32 + tt * 8 + hi * 4) = pk;
        }
    }
  }
}

extern "C" void kernel_launch(void* const* d_in, const int* in_sizes, int n_in,
                              void* d_out, int out_size, void* d_ws, size_t ws_size,
                              hipStream_t stream) {
  const float* x  = (const float*)d_in[0];
  const float* wq = (const float*)d_in[1];
  const float* wk = (const float*)d_in[2];
  const float* wv = (const float*)d_in[3];
  const float* wo = (const float*)d_in[4];
  float* out = (float*)d_out;

  const size_t SQDMs = (size_t)SEQ * DM;   // 8M elements
  short* Qb   = (short*)d_ws;
  short* Kb   = Qb + SQDMs;
  short* VTb  = Kb + SQDMs;
  short* Cb   = VTb + SQDMs;
  short* xbf  = Cb + SQDMs;
  short* wbuf = xbf + SQDMs;
  float2* tab = (float2*)(wbuf + (size_t)DM * DM);

  rope_tables_kernel<<<SEQ * 64 / 256, 256, 0, stream>>>(tab);
  f32_to_bf16_kernel<<<2048, 256, 0, stream>>>(x, xbf, (int)(SQDMs / 4));

  dim3 g(SEQ / 128, DM / 128);
  f32_to_bf16_kernel<<<2048, 256, 0, stream>>>(wq, wbuf, DM * DM / 4);
  gemm_rope_kernel<1><<<g, 256, 0, stream>>>(xbf, wbuf, Qb, tab);
  f32_to_bf16_kernel<<<2048, 256, 0, stream>>>(wk, wbuf, DM * DM / 4);
  gemm_rope_kernel<0><<<g, 256, 0, stream>>>(xbf, wbuf, Kb, tab);
  f32_to_bf16_kernel<<<2048, 256, 0, stream>>>(wv, wbuf, DM * DM / 4);
  gemm_async_kernel<2><<<g, 256, 0, stream>>>(xbf, wbuf, VTb, SEQ, DM, DM);

  flash_attn4_kernel<<<256, 512, 0, stream>>>(Qb, Kb, VTb, Cb);

  f32_to_bf16_kernel<<<2048, 256, 0, stream>>>(wo, wbuf, DM * DM / 4);
  gemm_async_kernel<0><<<g, 256, 0, stream>>>(Cb, wbuf, out, SEQ, DM, DM);
}